// Round 3
// baseline (3835.157 us; speedup 1.0000x reference)
//
#include <hip/hip_runtime.h>
#include <math.h>

// TGCN: B=16, T=12, N=1000, H=128, NL=2
#define BB 16
#define TT 12
#define NN 1000
#define HH 128
#define CC 129
#define NROW 16000
#define KP 1024           // padded node dim (k of stage-1, col dim of Gh/Grh)
#define CT 144            // stage-1 c-rows (0:x, 1..128:h, 129..143:zero)
#define SGS 72            // LDS stride for G/L tiles (bf16)
#define SPS 168           // LDS stride for P (bf16)
#define CP2 160           // stage-2 K (c padded)

typedef __attribute__((ext_vector_type(4))) float f32x4;
typedef __attribute__((ext_vector_type(8))) __bf16 bf16x8;

__device__ __forceinline__ float sigmoidf_(float x) { return 1.0f / (1.0f + expf(-x)); }

// ---------------- laplacian ----------------
__global__ void k_softmax(const float* __restrict__ adj, float* __restrict__ a) {
    int i = blockIdx.x;
    int t = threadIdx.x;
    __shared__ float red[256];
    float m = -1e30f;
    for (int j = t; j < NN; j += 256) m = fmaxf(m, adj[i * NN + j]);
    red[t] = m; __syncthreads();
    for (int s = 128; s > 0; s >>= 1) { if (t < s) red[t] = fmaxf(red[t], red[t + s]); __syncthreads(); }
    m = red[0]; __syncthreads();
    float sum = 0.f;
    for (int j = t; j < NN; j += 256) sum += expf(adj[i * NN + j] - m);
    red[t] = sum; __syncthreads();
    for (int s = 128; s > 0; s >>= 1) { if (t < s) red[t] += red[t + s]; __syncthreads(); }
    float inv = 1.0f / red[0];
    for (int j = t; j < NN; j += 256) a[i * NN + j] = expf(adj[i * NN + j] - m) * inv;
}

__global__ __launch_bounds__(256) void k_build_Lt(const float* __restrict__ a, __bf16* __restrict__ Lb) {
    __shared__ float s[64][65];
    int bi = blockIdx.x * 64;
    int bj = blockIdx.y * 64;
    int t = threadIdx.x;
    for (int q = t; q < 64 * 64; q += 256) {
        int r = q >> 6, c = q & 63;
        int jj = bj + r, ii = bi + c;
        s[r][c] = (jj < NN && ii < NN) ? a[jj * NN + ii] : 0.f;
    }
    __syncthreads();
    for (int q = t; q < 64 * 64; q += 256) {
        int r = q >> 6, c = q & 63;
        int ii = bi + r, jj = bj + c;
        if (ii < NN && jj < NN)
            Lb[(size_t)ii * KP + jj] = (__bf16)(0.5f * (s[c][r] + (ii == jj ? 1.0f : 0.0f)));
    }
}

// ---------------- one-time weight prep (f32 -> bf16, transposes/padding) ----------------
__global__ void k_prep(const float* __restrict__ wih, const float* __restrict__ whh,
                       const float* __restrict__ proj_w, const float* __restrict__ ow1,
                       const float* __restrict__ ow2, const float* __restrict__ gc1_w,
                       const float* __restrict__ gc2_w,
                       __bf16* __restrict__ WihB, __bf16* __restrict__ WhhB,
                       __bf16* __restrict__ projB, __bf16* __restrict__ w1B,
                       __bf16* __restrict__ w2B, __bf16* __restrict__ W1t,
                       __bf16* __restrict__ W2t) {
    int idx = blockIdx.x * 256 + threadIdx.x;
    if (idx < 49152) { WihB[idx] = (__bf16)wih[idx]; return; }
    idx -= 49152;
    if (idx < 49152) { WhhB[idx] = (__bf16)whh[idx]; return; }
    idx -= 49152;
    if (idx < 16384) { projB[idx] = (__bf16)proj_w[idx]; return; }
    idx -= 16384;
    if (idx < 32768) { w1B[idx] = (__bf16)ow1[idx]; return; }
    idx -= 32768;
    if (idx < 32768) { w2B[idx] = (__bf16)ow2[idx]; return; }
    idx -= 32768;
    if (idx < 2 * 256 * CP2) {
        int l = idx / (256 * CP2); int r = idx % (256 * CP2); int o = r / CP2, c = r % CP2;
        W1t[idx] = (c < CC) ? (__bf16)gc1_w[((size_t)l * CC + c) * 256 + o] : (__bf16)0.f;
        return;
    }
    idx -= 2 * 256 * CP2;
    if (idx < 2 * 128 * CP2) {
        int l = idx / (128 * CP2); int r = idx % (128 * CP2); int o = r / CP2, c = r % CP2;
        W2t[idx] = (c < CC) ? (__bf16)gc2_w[((size_t)l * CC + c) * 128 + o] : (__bf16)0.f;
    }
}

// ---------------- fused graph-conv + weight matmul + epilogue ----------------
// MODE 0: gates   (ODIM=256): sigmoid -> flat-chunk split -> Grh (r*h, transposed bf16), u
// MODE 1: cell    (ODIM=128): tanh -> h update -> +res -> LN -> mean -> Gh/outT/x_out
// Stage 1: P[m=64][c=144] = sum_k L[m0+m,k] * G[c,k]   (G row 0 = x, 1..128 = Gh rows)
// Stage 2: S[m][o] = sum_c P[m,c] * Wt[o,c]  (K = 160 zero-padded)
template<int MODE>
__global__ __launch_bounds__(256) void k_fused(
    const __bf16* __restrict__ Lb, const __bf16* __restrict__ Gh,
    const float* __restrict__ xsrc, int xstride,
    const __bf16* __restrict__ Wt, const float* __restrict__ bias,
    __bf16* __restrict__ Grh, float* __restrict__ u,
    float* __restrict__ h, const float* __restrict__ res_w, const float* __restrict__ res_b,
    const float* __restrict__ ln_g, const float* __restrict__ ln_b,
    float* __restrict__ x_out, __bf16* __restrict__ GhOut, __bf16* __restrict__ outT,
    int store_out) {
    constexpr int NOF = (MODE == 0) ? 16 : 8;
    constexpr int SMEMB = (MODE == 0) ? 36864 : 29952;
    __shared__ __align__(16) char smem[SMEMB];
    __shared__ float sScal[640];
    __bf16* sL = (__bf16*)smem;                    // [64][72]
    __bf16* sG = (__bf16*)(smem + 9216);           // [144][72]
    __bf16* sP = (__bf16*)smem;                    // [64][168] (overlay)
    __bf16* sGT = (__bf16*)smem;                   // MODE0: [256][72] (overlay)
    __bf16* sT = (__bf16*)smem;                    // MODE1: [128][72] (overlay)
    __bf16* sO = (__bf16*)smem;                    // MODE1: [64][136] (overlay)

    int tid = threadIdx.x;
    int b = blockIdx.y;
    int m0 = blockIdx.x * 64;
    int wv = tid >> 6, lane = tid & 63;
    int lr = lane & 15, lk = lane >> 4;

    if (MODE == 0) {
        if (tid < 256) sScal[tid] = bias[tid];
    } else {
        if (tid < 128) {
            sScal[tid] = bias[tid];
            sScal[128 + tid] = res_w[tid];
            sScal[256 + tid] = res_b[tid];
            sScal[384 + tid] = ln_g[tid];
            sScal[512 + tid] = ln_b[tid];
        }
    }

    f32x4 accp[9];
#pragma unroll
    for (int i = 0; i < 9; i++) accp[i] = (f32x4){0.f, 0.f, 0.f, 0.f};

    for (int kk = 0; kk < KP; kk += 64) {
        __syncthreads();
        // G tile [144][64]
#pragma unroll
        for (int it = 0; it < 5; ++it) {
            int q = tid + it * 256;
            if (q < CT * 8) {
                int r = q >> 3, ko = (q & 7) * 8, k = kk + ko;
                bf16x8 v;
                if (r == 0) {
                    if (k < 1000) {
                        float4 a0 = *(const float4*)&xsrc[(size_t)b * xstride + k];
                        float4 a1 = *(const float4*)&xsrc[(size_t)b * xstride + k + 4];
                        v[0] = (__bf16)a0.x; v[1] = (__bf16)a0.y; v[2] = (__bf16)a0.z; v[3] = (__bf16)a0.w;
                        v[4] = (__bf16)a1.x; v[5] = (__bf16)a1.y; v[6] = (__bf16)a1.z; v[7] = (__bf16)a1.w;
                    } else {
#pragma unroll
                        for (int e = 0; e < 8; e++) v[e] = (__bf16)0.f;
                    }
                } else if (r < 129) {
                    v = *(const bf16x8*)&Gh[((size_t)b * 128 + r - 1) * KP + k];
                } else {
#pragma unroll
                    for (int e = 0; e < 8; e++) v[e] = (__bf16)0.f;
                }
                *(bf16x8*)&sG[r * SGS + ko] = v;
            }
        }
        // L tile [64][64]
#pragma unroll
        for (int it = 0; it < 2; ++it) {
            int q = tid + it * 256;
            int r = q >> 3, ko = (q & 7) * 8;
            *(bf16x8*)&sL[r * SGS + ko] = *(const bf16x8*)&Lb[(size_t)(m0 + r) * KP + kk + ko];
        }
        __syncthreads();
#pragma unroll
        for (int ks = 0; ks < 64; ks += 32) {
            bf16x8 lf = *(const bf16x8*)&sL[(wv * 16 + lr) * SGS + ks + lk * 8];
#pragma unroll
            for (int cf = 0; cf < 9; cf++) {
                bf16x8 gf = *(const bf16x8*)&sG[(cf * 16 + lr) * SGS + ks + lk * 8];
                accp[cf] = __builtin_amdgcn_mfma_f32_16x16x32_bf16(lf, gf, accp[cf], 0, 0, 0);
            }
        }
    }
    __syncthreads();
    // P -> LDS bf16
#pragma unroll
    for (int cf = 0; cf < 9; cf++)
#pragma unroll
        for (int i = 0; i < 4; i++)
            sP[(wv * 16 + lk * 4 + i) * SPS + cf * 16 + lr] = (__bf16)accp[cf][i];
    // zero pad cols 144..159
    for (int q = tid; q < 64 * 16; q += 256) sP[(q >> 4) * SPS + 144 + (q & 15)] = (__bf16)0.f;
    __syncthreads();

    // Stage 2
    f32x4 accs[NOF];
#pragma unroll
    for (int i = 0; i < NOF; i++) accs[i] = (f32x4){0.f, 0.f, 0.f, 0.f};
#pragma unroll
    for (int kk2 = 0; kk2 < CP2; kk2 += 32) {
        bf16x8 pa = *(const bf16x8*)&sP[(wv * 16 + lr) * SPS + kk2 + lk * 8];
#pragma unroll
        for (int of = 0; of < NOF; of++) {
            bf16x8 wb = *(const bf16x8*)&Wt[(size_t)(of * 16 + lr) * CP2 + kk2 + lk * 8];
            accs[of] = __builtin_amdgcn_mfma_f32_16x16x32_bf16(pa, wb, accs[of], 0, 0, 0);
        }
    }
    __syncthreads();

    if (MODE == 0) {
        // gates epilogue: g = sigmoid(S + b1). node rn = m. rn<500 -> r*h, else u.
        if (m0 + 64 <= 500) {
            // pure-rh tile: stage gates into sGT [o=256][m=64]
#pragma unroll
            for (int of = 0; of < 16; of++) {
                int o = of * 16 + lr;
                float bv = sScal[o];
#pragma unroll
                for (int i = 0; i < 4; i++)
                    sGT[o * SGS + wv * 16 + lk * 4 + i] = (__bf16)sigmoidf_(accs[of][i] + bv);
            }
            __syncthreads();
            // phase B: rh[j][m'] = g[(m'&1)*128+j][m'>>1] * h[j][m']  (vectorized over m')
            for (int q = tid; q < 128 * 16; q += 256) {
                int j = q >> 4;
                int rnc = (q & 15) * 4;
                int mpl = rnc * 2;
                size_t gidx = ((size_t)b * 128 + j) * KP + 2 * m0 + mpl;
                bf16x8 hv = *(const bf16x8*)&Gh[gidx];
                bf16x8 rv;
#pragma unroll
                for (int e = 0; e < 8; e++) {
                    int rnl = rnc + (e >> 1);
                    int hi = e & 1;
                    float g = (float)sGT[(hi * 128 + j) * SGS + rnl];
                    rv[e] = (__bf16)(g * (float)hv[e]);
                }
                *(bf16x8*)&Grh[gidx] = rv;
            }
        } else {
            // mixed / pure-u tiles: element-wise
#pragma unroll
            for (int of = 0; of < 16; of++) {
                int o = of * 16 + lr;
                int j = o & 127, hi = o >> 7;
                float bv = sScal[o];
#pragma unroll
                for (int i = 0; i < 4; i++) {
                    int m = m0 + wv * 16 + lk * 4 + i;
                    if (m >= 1000) continue;
                    float g = sigmoidf_(accs[of][i] + bv);
                    if (m < 500) {
                        size_t gi = ((size_t)b * 128 + j) * KP + 2 * m + hi;
                        Grh[gi] = (__bf16)(g * (float)Gh[gi]);
                    } else {
                        u[((size_t)b * 1000 + 2 * (m - 500) + hi) * HH + j] = g;
                    }
                }
            }
        }
    } else {
        // cell epilogue
        float s_[4] = {0.f, 0.f, 0.f, 0.f}, ss_[4] = {0.f, 0.f, 0.f, 0.f};
        float hnv[8][4];
#pragma unroll
        for (int of = 0; of < 8; of++) {
            int j = of * 16 + lr;
            float b2v = sScal[j], rwv = sScal[128 + j], rbv = sScal[256 + j];
#pragma unroll
            for (int i = 0; i < 4; i++) {
                int m = m0 + wv * 16 + lk * 4 + i;
                size_t ri = ((size_t)b * 1000 + m) * HH + j;
                float cv = tanhf(accs[of][i] + b2v);
                float uu = u[ri];
                float hv = h[ri];
                float hn = uu * hv + (1.f - uu) * cv;
                if (m < 1000) h[ri] = hn;
                hnv[of][i] = hn;
                float xv = (m < 1000) ? xsrc[(size_t)b * xstride + m] : 0.f;
                float y = hn + xv * rwv + rbv;
                accs[of][i] = y;
                s_[i] += y; ss_[i] += y * y;
            }
        }
#pragma unroll
        for (int msk = 1; msk < 16; msk <<= 1)
#pragma unroll
            for (int i = 0; i < 4; i++) {
                s_[i] += __shfl_xor(s_[i], msk);
                ss_[i] += __shfl_xor(ss_[i], msk);
            }
        float mu_[4], rs_[4];
#pragma unroll
        for (int i = 0; i < 4; i++) {
            float mu = s_[i] * (1.f / 128.f);
            float var = ss_[i] * (1.f / 128.f) - mu * mu;
            mu_[i] = mu; rs_[i] = rsqrtf(var + 1e-5f);
        }
        float xs_[4] = {0.f, 0.f, 0.f, 0.f};
#pragma unroll
        for (int of = 0; of < 8; of++) {
            int j = of * 16 + lr;
            float lg = sScal[384 + j], lb2 = sScal[512 + j];
#pragma unroll
            for (int i = 0; i < 4; i++) {
                float ov = (accs[of][i] - mu_[i]) * rs_[i] * lg + lb2;
                accs[of][i] = ov;
                xs_[i] += ov;
            }
        }
#pragma unroll
        for (int msk = 1; msk < 16; msk <<= 1)
#pragma unroll
            for (int i = 0; i < 4; i++) xs_[i] += __shfl_xor(xs_[i], msk);
        if (lr == 0) {
#pragma unroll
            for (int i = 0; i < 4; i++) {
                int m = m0 + wv * 16 + lk * 4 + i;
                if (m < 1000) x_out[(size_t)b * 1000 + m] = xs_[i] * (1.f / 128.f);
            }
        }
        // stage hn transposed -> GhOut
        __syncthreads();
#pragma unroll
        for (int of = 0; of < 8; of++)
#pragma unroll
            for (int i = 0; i < 4; i++)
                sT[(of * 16 + lr) * SGS + wv * 16 + lk * 4 + i] = (__bf16)hnv[of][i];
        __syncthreads();
        for (int q = tid; q < 128 * 8; q += 256) {
            int j = q >> 3, mc = (q & 7) * 8;
            if (m0 + mc < 1000)
                *(bf16x8*)&GhOut[((size_t)b * 128 + j) * KP + m0 + mc] = *(const bf16x8*)&sT[j * SGS + mc];
        }
        if (store_out) {
            __syncthreads();
#pragma unroll
            for (int of = 0; of < 8; of++)
#pragma unroll
                for (int i = 0; i < 4; i++)
                    sO[(wv * 16 + lk * 4 + i) * 136 + of * 16 + lr] = (__bf16)accs[of][i];
            __syncthreads();
            for (int q = tid; q < 64 * 16; q += 256) {
                int ml = q >> 4, jc = (q & 15) * 8;
                int m = m0 + ml;
                if (m < 1000)
                    *(bf16x8*)&outT[((size_t)b * 1000 + m) * HH + jc] = *(const bf16x8*)&sO[ml * 136 + jc];
            }
        }
    }
}

// ---------------- GRU cell, MFMA (one timestep) ----------------
__global__ __launch_bounds__(256) void k_gru_mfma(const __bf16* __restrict__ Xb,
                                                  float* __restrict__ hg,
                                                  __bf16* __restrict__ Hb,
                                                  const __bf16* __restrict__ WihB,
                                                  const __bf16* __restrict__ WhhB,
                                                  const float* __restrict__ bih,
                                                  const float* __restrict__ bhh) {
    __shared__ float sB[512];
    int tid = threadIdx.x;
    int r0 = blockIdx.x * 64;
    int wv = tid >> 6, lane = tid & 63;
    int lr = lane & 15, lk = lane >> 4;
    if (tid < 128) {
        sB[tid] = bih[tid] + bhh[tid];
        sB[128 + tid] = bih[128 + tid] + bhh[128 + tid];
        sB[256 + tid] = bih[256 + tid];
        sB[384 + tid] = bhh[256 + tid];
    }
    __syncthreads();

    f32x4 rz[16], ni[8], nh[8];
#pragma unroll
    for (int i = 0; i < 16; i++) rz[i] = (f32x4){0.f, 0.f, 0.f, 0.f};
#pragma unroll
    for (int i = 0; i < 8; i++) { ni[i] = (f32x4){0.f, 0.f, 0.f, 0.f}; nh[i] = (f32x4){0.f, 0.f, 0.f, 0.f}; }

    int arow = r0 + wv * 16 + lr;
#pragma unroll
    for (int kk = 0; kk < 128; kk += 32) {
        bf16x8 xa = *(const bf16x8*)&Xb[(size_t)arow * HH + kk + lk * 8];
        bf16x8 ha = *(const bf16x8*)&Hb[(size_t)arow * HH + kk + lk * 8];
#pragma unroll
        for (int f = 0; f < 16; f++) {
            bf16x8 wi = *(const bf16x8*)&WihB[(size_t)(f * 16 + lr) * HH + kk + lk * 8];
            rz[f] = __builtin_amdgcn_mfma_f32_16x16x32_bf16(xa, wi, rz[f], 0, 0, 0);
            bf16x8 wh = *(const bf16x8*)&WhhB[(size_t)(f * 16 + lr) * HH + kk + lk * 8];
            rz[f] = __builtin_amdgcn_mfma_f32_16x16x32_bf16(ha, wh, rz[f], 0, 0, 0);
        }
#pragma unroll
        for (int f = 0; f < 8; f++) {
            bf16x8 wi = *(const bf16x8*)&WihB[(size_t)(256 + f * 16 + lr) * HH + kk + lk * 8];
            ni[f] = __builtin_amdgcn_mfma_f32_16x16x32_bf16(xa, wi, ni[f], 0, 0, 0);
            bf16x8 wh = *(const bf16x8*)&WhhB[(size_t)(256 + f * 16 + lr) * HH + kk + lk * 8];
            nh[f] = __builtin_amdgcn_mfma_f32_16x16x32_bf16(ha, wh, nh[f], 0, 0, 0);
        }
    }
#pragma unroll
    for (int f = 0; f < 8; f++) {
        int j = f * 16 + lr;
        float br = sB[j], bz = sB[128 + j], bni = sB[256 + j], bnh = sB[384 + j];
#pragma unroll
        for (int i = 0; i < 4; i++) {
            int row = r0 + wv * 16 + lk * 4 + i;
            float rg = sigmoidf_(rz[f][i] + br);
            float zg = sigmoidf_(rz[f + 8][i] + bz);
            float hv = hg[(size_t)row * HH + j];
            float ng = tanhf(ni[f][i] + bni + rg * (nh[f][i] + bnh));
            float hp = (1.f - zg) * ng + zg * hv;
            hg[(size_t)row * HH + j] = hp;
            Hb[(size_t)row * HH + j] = (__bf16)hp;
        }
    }
}

// ---------------- head: proj -> relu MLP -> out, MFMA ----------------
__global__ __launch_bounds__(256) void k_head_mfma(const __bf16* __restrict__ Hb,
                                                   const __bf16* __restrict__ projB,
                                                   const float* __restrict__ pb,
                                                   const __bf16* __restrict__ w1B,
                                                   const float* __restrict__ b1,
                                                   const __bf16* __restrict__ w2B,
                                                   const float* __restrict__ b2,
                                                   float* __restrict__ out) {
    __shared__ __align__(16) __bf16 sH1[64 * 136];
    __shared__ __align__(16) __bf16 sH2[64 * 264];
    int tid = threadIdx.x;
    int r0 = blockIdx.x * 64;
    int wv = tid >> 6, lane = tid & 63;
    int lr = lane & 15, lk = lane >> 4;
    int arow = r0 + wv * 16 + lr;

    f32x4 a1[8];
#pragma unroll
    for (int i = 0; i < 8; i++) a1[i] = (f32x4){0.f, 0.f, 0.f, 0.f};
#pragma unroll
    for (int kk = 0; kk < 128; kk += 32) {
        bf16x8 xa = *(const bf16x8*)&Hb[(size_t)arow * HH + kk + lk * 8];
#pragma unroll
        for (int f = 0; f < 8; f++) {
            bf16x8 wb = *(const bf16x8*)&projB[(size_t)(f * 16 + lr) * HH + kk + lk * 8];
            a1[f] = __builtin_amdgcn_mfma_f32_16x16x32_bf16(xa, wb, a1[f], 0, 0, 0);
        }
    }
#pragma unroll
    for (int f = 0; f < 8; f++) {
        int j = f * 16 + lr;
        float bv = pb[j];
#pragma unroll
        for (int i = 0; i < 4; i++)
            sH1[(wv * 16 + lk * 4 + i) * 136 + j] = (__bf16)(a1[f][i] + bv);
    }
    __syncthreads();

    f32x4 a2[16];
#pragma unroll
    for (int i = 0; i < 16; i++) a2[i] = (f32x4){0.f, 0.f, 0.f, 0.f};
#pragma unroll
    for (int kk = 0; kk < 128; kk += 32) {
        bf16x8 pa = *(const bf16x8*)&sH1[(wv * 16 + lr) * 136 + kk + lk * 8];
#pragma unroll
        for (int f = 0; f < 16; f++) {
            bf16x8 wb = *(const bf16x8*)&w1B[(size_t)(f * 16 + lr) * HH + kk + lk * 8];
            a2[f] = __builtin_amdgcn_mfma_f32_16x16x32_bf16(pa, wb, a2[f], 0, 0, 0);
        }
    }
    __syncthreads();
#pragma unroll
    for (int f = 0; f < 16; f++) {
        int o = f * 16 + lr;
        float bv = b1[o];
#pragma unroll
        for (int i = 0; i < 4; i++)
            sH2[(wv * 16 + lk * 4 + i) * 264 + o] = (__bf16)fmaxf(a2[f][i] + bv, 0.f);
    }
    __syncthreads();

    f32x4 a3[8];
#pragma unroll
    for (int i = 0; i < 8; i++) a3[i] = (f32x4){0.f, 0.f, 0.f, 0.f};
#pragma unroll
    for (int kk = 0; kk < 256; kk += 32) {
        bf16x8 pa = *(const bf16x8*)&sH2[(wv * 16 + lr) * 264 + kk + lk * 8];
#pragma unroll
        for (int f = 0; f < 8; f++) {
            bf16x8 wb = *(const bf16x8*)&w2B[(size_t)(f * 16 + lr) * 256 + kk + lk * 8];
            a3[f] = __builtin_amdgcn_mfma_f32_16x16x32_bf16(pa, wb, a3[f], 0, 0, 0);
        }
    }
#pragma unroll
    for (int f = 0; f < 8; f++) {
        int j = f * 16 + lr;
        float bv = b2[j];
#pragma unroll
        for (int i = 0; i < 4; i++)
            out[(size_t)(r0 + wv * 16 + lk * 4 + i) * HH + j] = a3[f][i] + bv;
    }
}

extern "C" void kernel_launch(void* const* d_in, const int* in_sizes, int n_in,
                              void* d_out, int out_size, void* d_ws, size_t ws_size,
                              hipStream_t stream) {
    const float* inp    = (const float*)d_in[0];
    const float* adj    = (const float*)d_in[1];
    const float* gc1_w  = (const float*)d_in[2];
    const float* gc1_b  = (const float*)d_in[3];
    const float* gc2_w  = (const float*)d_in[4];
    const float* gc2_b  = (const float*)d_in[5];
    const float* ln_g   = (const float*)d_in[6];
    const float* ln_b   = (const float*)d_in[7];
    const float* res_w  = (const float*)d_in[8];
    const float* res_b  = (const float*)d_in[9];
    const float* wih    = (const float*)d_in[10];
    const float* whh    = (const float*)d_in[11];
    const float* bih    = (const float*)d_in[12];
    const float* bhh    = (const float*)d_in[13];
    const float* proj_w = (const float*)d_in[14];
    const float* proj_b = (const float*)d_in[15];
    const float* ow1    = (const float*)d_in[16];
    const float* ob1    = (const float*)d_in[17];
    const float* ow2    = (const float*)d_in[18];
    const float* ob2    = (const float*)d_in[19];
    float* out = (float*)d_out;

    char* ws = (char*)d_ws;
    size_t off = 0;
    __bf16* Lb  = (__bf16*)(ws + off); off += (size_t)KP * KP * 2;        // 2 MB
    __bf16* Gh0 = (__bf16*)(ws + off); off += (size_t)2048 * KP * 2;      // 4 MB
    __bf16* Gh1 = (__bf16*)(ws + off); off += (size_t)2048 * KP * 2;
    __bf16* Grh = (__bf16*)(ws + off); off += (size_t)2048 * KP * 2;
    float* h0   = (float*)(ws + off);  off += (size_t)NROW * HH * 4;
    float* h1   = (float*)(ws + off);  off += (size_t)NROW * HH * 4;
    float* hg   = (float*)(ws + off);  off += (size_t)NROW * HH * 4;
    __bf16* Hb  = (__bf16*)(ws + off); off += (size_t)NROW * HH * 2;
    float* u    = (float*)(ws + off);  off += (size_t)NROW * HH * 4;
    __bf16* outT= (__bf16*)(ws + off); off += (size_t)NROW * HH * 2;
    float* xA   = (float*)(ws + off);  off += NROW * 4;
    float* xB   = (float*)(ws + off);  off += NROW * 4;
    __bf16* W1t = (__bf16*)(ws + off); off += (size_t)2 * 256 * CP2 * 2;
    __bf16* W2t = (__bf16*)(ws + off); off += (size_t)2 * 128 * CP2 * 2;
    __bf16* WihB= (__bf16*)(ws + off); off += 49152 * 2;
    __bf16* WhhB= (__bf16*)(ws + off); off += 49152 * 2;
    __bf16* projB=(__bf16*)(ws + off); off += 16384 * 2;
    __bf16* w1B = (__bf16*)(ws + off); off += 32768 * 2;
    __bf16* w2B = (__bf16*)(ws + off); off += 32768 * 2;
    float* a_sm = u;   // overlay: softmax scratch used before u's first write

    hipMemsetAsync(Lb, 0, (size_t)KP * KP * 2 + 3 * (size_t)2048 * KP * 2, stream); // Lb,Gh0,Gh1,Grh
    hipMemsetAsync(h0, 0, (size_t)NROW * HH * 8, stream);                            // h0,h1
    hipMemsetAsync(hg, 0, (size_t)NROW * HH * 6, stream);                            // hg,Hb

    k_softmax<<<NN, 256, 0, stream>>>(adj, a_sm);
    k_build_Lt<<<dim3(16, 16), 256, 0, stream>>>(a_sm, Lb);
    k_prep<<<1184, 256, 0, stream>>>(wih, whh, proj_w, ow1, ow2, gc1_w, gc2_w,
                                     WihB, WhhB, projB, w1B, w2B, W1t, W2t);

    dim3 fgrid(16, 16);
    for (int t = 0; t < TT; t++) {
        const float* xs0 = inp + (size_t)t * NN;
        // layer 0
        k_fused<0><<<fgrid, 256, 0, stream>>>(Lb, Gh0, xs0, TT * NN, W1t, gc1_b,
                                              Grh, u, nullptr, nullptr, nullptr, nullptr,
                                              nullptr, nullptr, nullptr, nullptr, 0);
        k_fused<1><<<fgrid, 256, 0, stream>>>(Lb, Grh, xs0, TT * NN, W2t, gc2_b,
                                              nullptr, u, h0, res_w, res_b, ln_g, ln_b,
                                              xB, Gh0, outT, 0);
        // layer 1
        k_fused<0><<<fgrid, 256, 0, stream>>>(Lb, Gh1, xB, NN, W1t + 256 * CP2, gc1_b + 256,
                                              Grh, u, nullptr, nullptr, nullptr, nullptr,
                                              nullptr, nullptr, nullptr, nullptr, 0);
        k_fused<1><<<fgrid, 256, 0, stream>>>(Lb, Grh, xB, NN, W2t + 128 * CP2, gc2_b + 128,
                                              nullptr, u, h1, res_w, res_b, ln_g + 128, ln_b + 128,
                                              xA, Gh1, outT, 1);
        k_gru_mfma<<<250, 256, 0, stream>>>(outT, hg, Hb, WihB, WhhB, bih, bhh);
    }
    k_head_mfma<<<250, 256, 0, stream>>>(Hb, projB, proj_b, w1B, ob1, w2B, ob2, out);
}

// Round 4
// 2268.264 us; speedup vs baseline: 1.6908x; 1.6908x over previous
//
#include <hip/hip_runtime.h>
#include <math.h>

// TGCN: B=16, T=12, N=1000, H=128, NL=2
#define BB 16
#define TT 12
#define NN 1000
#define HH 128
#define CC 129
#define NROW 16000
#define KP 1024           // padded node dim
#define SGS 72            // LDS stride for G/L tiles (bf16)
#define SPS 168           // LDS stride for P (bf16)
#define PRS 148           // LDS stride for partial P (f32)
#define CP2 160           // stage-2 K (c padded)

typedef __attribute__((ext_vector_type(4))) float f32x4;
typedef __attribute__((ext_vector_type(8))) __bf16 bf16x8;

__device__ __forceinline__ float sigmoidf_(float x) { return 1.0f / (1.0f + expf(-x)); }

__device__ __forceinline__ bf16x8 bzero8() {
    bf16x8 v;
#pragma unroll
    for (int e = 0; e < 8; e++) v[e] = (__bf16)0.f;
    return v;
}

// ---------------- laplacian ----------------
__global__ void k_softmax(const float* __restrict__ adj, float* __restrict__ a) {
    int i = blockIdx.x;
    int t = threadIdx.x;
    __shared__ float red[256];
    float m = -1e30f;
    for (int j = t; j < NN; j += 256) m = fmaxf(m, adj[i * NN + j]);
    red[t] = m; __syncthreads();
    for (int s = 128; s > 0; s >>= 1) { if (t < s) red[t] = fmaxf(red[t], red[t + s]); __syncthreads(); }
    m = red[0]; __syncthreads();
    float sum = 0.f;
    for (int j = t; j < NN; j += 256) sum += expf(adj[i * NN + j] - m);
    red[t] = sum; __syncthreads();
    for (int s = 128; s > 0; s >>= 1) { if (t < s) red[t] += red[t + s]; __syncthreads(); }
    float inv = 1.0f / red[0];
    for (int j = t; j < NN; j += 256) a[i * NN + j] = expf(adj[i * NN + j] - m) * inv;
}

__global__ __launch_bounds__(256) void k_build_Lt(const float* __restrict__ a, __bf16* __restrict__ Lb) {
    __shared__ float s[64][65];
    int bi = blockIdx.x * 64;
    int bj = blockIdx.y * 64;
    int t = threadIdx.x;
    for (int q = t; q < 64 * 64; q += 256) {
        int r = q >> 6, c = q & 63;
        int jj = bj + r, ii = bi + c;
        s[r][c] = (jj < NN && ii < NN) ? a[jj * NN + ii] : 0.f;
    }
    __syncthreads();
    for (int q = t; q < 64 * 64; q += 256) {
        int r = q >> 6, c = q & 63;
        int ii = bi + r, jj = bj + c;
        if (ii < NN && jj < NN)
            Lb[(size_t)ii * KP + jj] = (__bf16)(0.5f * (s[c][r] + (ii == jj ? 1.0f : 0.0f)));
    }
}

// ---------------- one-time weight prep ----------------
__global__ void k_prep(const float* __restrict__ wih, const float* __restrict__ whh,
                       const float* __restrict__ proj_w, const float* __restrict__ ow1,
                       const float* __restrict__ ow2, const float* __restrict__ gc1_w,
                       const float* __restrict__ gc2_w,
                       __bf16* __restrict__ WihB, __bf16* __restrict__ WhhB,
                       __bf16* __restrict__ projB, __bf16* __restrict__ w1B,
                       __bf16* __restrict__ w2B, __bf16* __restrict__ W1t,
                       __bf16* __restrict__ W2t) {
    int idx = blockIdx.x * 256 + threadIdx.x;
    if (idx < 49152) { WihB[idx] = (__bf16)wih[idx]; return; }
    idx -= 49152;
    if (idx < 49152) { WhhB[idx] = (__bf16)whh[idx]; return; }
    idx -= 49152;
    if (idx < 16384) { projB[idx] = (__bf16)proj_w[idx]; return; }
    idx -= 16384;
    if (idx < 32768) { w1B[idx] = (__bf16)ow1[idx]; return; }
    idx -= 32768;
    if (idx < 32768) { w2B[idx] = (__bf16)ow2[idx]; return; }
    idx -= 32768;
    if (idx < 2 * 256 * CP2) {
        int l = idx / (256 * CP2); int r = idx % (256 * CP2); int o = r / CP2, c = r % CP2;
        W1t[idx] = (c < CC) ? (__bf16)gc1_w[((size_t)l * CC + c) * 256 + o] : (__bf16)0.f;
        return;
    }
    idx -= 2 * 256 * CP2;
    if (idx < 2 * 128 * CP2) {
        int l = idx / (128 * CP2); int r = idx % (128 * CP2); int o = r / CP2, c = r % CP2;
        W2t[idx] = (c < CC) ? (__bf16)gc2_w[((size_t)l * CC + c) * 128 + o] : (__bf16)0.f;
    }
}

// Xall[t][b][k] = bf16(inp[b][t][k]), zero pad k>=1000
__global__ void k_prep_x(const float* __restrict__ inp, __bf16* __restrict__ Xall) {
    int idx = blockIdx.x * 256 + threadIdx.x;
    if (idx >= TT * BB * 1024) return;
    int t = idx / (BB * 1024);
    int r = idx % (BB * 1024);
    int b = r >> 10, k = r & 1023;
    Xall[idx] = (k < 1000) ? (__bf16)inp[(size_t)b * TT * NN + t * NN + k] : (__bf16)0.f;
}

// ---------------- fused graph-conv + weight matmul + epilogue ----------------
// 512 threads = 8 waves: wk = k-half (0/1), wm = m-quarter (16 rows of the 64-row tile).
// Stage 1: P[m][c=144] = sum_k L[m0+m,k]*G[c,k]; G row0 = x(bf16), rows1..128 = Gh, 129..143 = 0
// Reduction of k-halves in LDS f32, then stage 2 + epilogue on waves 0-3 (round-3 code).
template<int MODE>
__global__ __launch_bounds__(512) void k_fused(
    const __bf16* __restrict__ Lb, const __bf16* __restrict__ Gh,
    const __bf16* __restrict__ xb,
    const float* __restrict__ xsrc, int xstride,
    const __bf16* __restrict__ Wt, const float* __restrict__ bias,
    __bf16* __restrict__ Grh, float* __restrict__ u,
    float* __restrict__ h, const float* __restrict__ res_w, const float* __restrict__ res_b,
    const float* __restrict__ ln_g, const float* __restrict__ ln_b,
    float* __restrict__ x_out, __bf16* __restrict__ xb_out,
    __bf16* __restrict__ GhOut, __bf16* __restrict__ outT, int store_out) {
    __shared__ __align__(16) char smem[59904];
    __shared__ float sScal[640];
    int tid = threadIdx.x;
    int b = blockIdx.y;
    int m0 = blockIdx.x * 64;
    int wave = tid >> 6, lane = tid & 63;
    int lr = lane & 15, lk = lane >> 4;
    int wk = tid >> 8;            // k-half
    int wm = wave & 3;            // m-quarter
    int tid_h = tid & 255;

    __bf16* sL = (__bf16*)(smem + wk * 29952);           // [64][72]
    __bf16* sG = (__bf16*)(smem + wk * 29952 + 9216);    // [144][72]
    float* Pred = (float*)smem;                          // [64][148] f32 (overlay)
    __bf16* sP = (__bf16*)(smem + 37888);                // [64][168] (overlay)
    __bf16* sGT = (__bf16*)smem;                         // MODE0 [256][72] (overlay)
    __bf16* sT = (__bf16*)smem;                          // MODE1 [128][72] (overlay)
    __bf16* sO = (__bf16*)smem;                          // MODE1 [64][136] (overlay)

    if (MODE == 0) {
        if (tid < 256) sScal[tid] = bias[tid];
    } else {
        if (tid < 128) {
            sScal[tid] = bias[tid];
            sScal[128 + tid] = res_w[tid];
            sScal[256 + tid] = res_b[tid];
            sScal[384 + tid] = ln_g[tid];
            sScal[512 + tid] = ln_b[tid];
        }
    }

    int kbase = wk * 512;
    bf16x8 gbuf[5], lbuf[2];

#define LOADG(IT)                                                                     \
    {                                                                                 \
        int k0 = kbase + (IT) * 64;                                                   \
        _Pragma("unroll")                                                             \
        for (int c = 0; c < 5; c++) {                                                 \
            int q = tid_h + c * 256;                                                  \
            if (q < 1152) {                                                           \
                int r = q >> 3, ko = (q & 7) * 8, k = k0 + ko;                        \
                if (r < 129) {                                                        \
                    const __bf16* p = (r == 0) ? (xb + (size_t)b * 1024 + k)          \
                                               : (Gh + ((size_t)b * 128 + r - 1) * KP + k); \
                    gbuf[c] = *(const bf16x8*)p;                                      \
                } else gbuf[c] = bzero8();                                            \
            }                                                                         \
        }                                                                             \
        _Pragma("unroll")                                                             \
        for (int c = 0; c < 2; c++) {                                                 \
            int q = tid_h + c * 256;                                                  \
            int r = q >> 3, ko = (q & 7) * 8;                                         \
            lbuf[c] = *(const bf16x8*)&Lb[(size_t)(m0 + r) * KP + k0 + ko];           \
        }                                                                             \
    }

    f32x4 accp[9];
#pragma unroll
    for (int i = 0; i < 9; i++) accp[i] = (f32x4){0.f, 0.f, 0.f, 0.f};

    LOADG(0);
    for (int it = 0; it < 8; ++it) {
        __syncthreads();
        // write staged regs -> LDS
#pragma unroll
        for (int c = 0; c < 5; c++) {
            int q = tid_h + c * 256;
            if (q < 1152) { int r = q >> 3, ko = (q & 7) * 8; *(bf16x8*)&sG[r * SGS + ko] = gbuf[c]; }
        }
#pragma unroll
        for (int c = 0; c < 2; c++) {
            int q = tid_h + c * 256;
            int r = q >> 3, ko = (q & 7) * 8;
            *(bf16x8*)&sL[r * SGS + ko] = lbuf[c];
        }
        if (it < 7) LOADG(it + 1);
        __syncthreads();
#pragma unroll
        for (int ks = 0; ks < 64; ks += 32) {
            bf16x8 lf = *(const bf16x8*)&sL[(wm * 16 + lr) * SGS + ks + lk * 8];
#pragma unroll
            for (int cf = 0; cf < 9; cf++) {
                bf16x8 gf = *(const bf16x8*)&sG[(cf * 16 + lr) * SGS + ks + lk * 8];
                accp[cf] = __builtin_amdgcn_mfma_f32_16x16x32_bf16(lf, gf, accp[cf], 0, 0, 0);
            }
        }
    }
    __syncthreads();
    // k-half reduction: wk1 writes partials; wk0 adds and emits bf16 P
    if (wk == 1) {
#pragma unroll
        for (int cf = 0; cf < 9; cf++)
#pragma unroll
            for (int i = 0; i < 4; i++)
                Pred[(wm * 16 + lk * 4 + i) * PRS + cf * 16 + lr] = accp[cf][i];
    }
    __syncthreads();
    if (wk == 0) {
#pragma unroll
        for (int cf = 0; cf < 9; cf++)
#pragma unroll
            for (int i = 0; i < 4; i++) {
                float v = accp[cf][i] + Pred[(wm * 16 + lk * 4 + i) * PRS + cf * 16 + lr];
                sP[(wm * 16 + lk * 4 + i) * SPS + cf * 16 + lr] = (__bf16)v;
            }
    } else {
        for (int q = tid_h; q < 64 * 16; q += 256) sP[(q >> 4) * SPS + 144 + (q & 15)] = (__bf16)0.f;
    }
    __syncthreads();

    // Stage 2 (waves 0-3)
    constexpr int NOF = (MODE == 0) ? 16 : 8;
    f32x4 accs[NOF];
    if (wk == 0) {
#pragma unroll
        for (int i = 0; i < NOF; i++) accs[i] = (f32x4){0.f, 0.f, 0.f, 0.f};
#pragma unroll
        for (int kk2 = 0; kk2 < CP2; kk2 += 32) {
            bf16x8 pa = *(const bf16x8*)&sP[(wm * 16 + lr) * SPS + kk2 + lk * 8];
#pragma unroll
            for (int of = 0; of < NOF; of++) {
                bf16x8 wb = *(const bf16x8*)&Wt[(size_t)(of * 16 + lr) * CP2 + kk2 + lk * 8];
                accs[of] = __builtin_amdgcn_mfma_f32_16x16x32_bf16(pa, wb, accs[of], 0, 0, 0);
            }
        }
    }
    __syncthreads();

    if (MODE == 0) {
        bool cleanr = (m0 + 64 <= 500);
        if (cleanr) {
            if (wk == 0) {
#pragma unroll
                for (int of = 0; of < 16; of++) {
                    int o = of * 16 + lr;
                    float bv = sScal[o];
#pragma unroll
                    for (int i = 0; i < 4; i++)
                        sGT[o * SGS + wm * 16 + lk * 4 + i] = (__bf16)sigmoidf_(accs[of][i] + bv);
                }
            }
            __syncthreads();
            for (int q = tid; q < 128 * 16; q += 512) {
                int j = q >> 4;
                int rnc = (q & 15) * 4;
                int mpl = rnc * 2;
                size_t gidx = ((size_t)b * 128 + j) * KP + 2 * m0 + mpl;
                bf16x8 hv = *(const bf16x8*)&Gh[gidx];
                bf16x8 rv;
#pragma unroll
                for (int e = 0; e < 8; e++) {
                    int rnl = rnc + (e >> 1);
                    int hi = e & 1;
                    float g = (float)sGT[(hi * 128 + j) * SGS + rnl];
                    rv[e] = (__bf16)(g * (float)hv[e]);
                }
                *(bf16x8*)&Grh[gidx] = rv;
            }
        } else {
            if (wk == 0) {
#pragma unroll
                for (int of = 0; of < 16; of++) {
                    int o = of * 16 + lr;
                    int j = o & 127, hi = o >> 7;
                    float bv = sScal[o];
#pragma unroll
                    for (int i = 0; i < 4; i++) {
                        int m = m0 + wm * 16 + lk * 4 + i;
                        if (m >= 1000) continue;
                        float g = sigmoidf_(accs[of][i] + bv);
                        if (m < 500) {
                            size_t gi = ((size_t)b * 128 + j) * KP + 2 * m + hi;
                            Grh[gi] = (__bf16)(g * (float)Gh[gi]);
                        } else {
                            u[((size_t)b * 1000 + 2 * (m - 500) + hi) * HH + j] = g;
                        }
                    }
                }
            }
        }
    } else {
        float hnv[8][4];
        float mu_[4], rs_[4];
        if (wk == 0) {
            float s_[4] = {0.f, 0.f, 0.f, 0.f}, ss_[4] = {0.f, 0.f, 0.f, 0.f};
#pragma unroll
            for (int of = 0; of < 8; of++) {
                int j = of * 16 + lr;
                float b2v = sScal[j], rwv = sScal[128 + j], rbv = sScal[256 + j];
#pragma unroll
                for (int i = 0; i < 4; i++) {
                    int m = m0 + wm * 16 + lk * 4 + i;
                    size_t ri = ((size_t)b * 1000 + m) * HH + j;
                    float cv = tanhf(accs[of][i] + b2v);
                    float uu = u[ri];
                    float hv = h[ri];
                    float hn = uu * hv + (1.f - uu) * cv;
                    if (m < 1000) h[ri] = hn;
                    hnv[of][i] = hn;
                    float xv = (m < 1000) ? xsrc[(size_t)b * xstride + m] : 0.f;
                    float y = hn + xv * rwv + rbv;
                    accs[of][i] = y;
                    s_[i] += y; ss_[i] += y * y;
                }
            }
#pragma unroll
            for (int msk = 1; msk < 16; msk <<= 1)
#pragma unroll
                for (int i = 0; i < 4; i++) {
                    s_[i] += __shfl_xor(s_[i], msk);
                    ss_[i] += __shfl_xor(ss_[i], msk);
                }
#pragma unroll
            for (int i = 0; i < 4; i++) {
                float mu = s_[i] * (1.f / 128.f);
                float var = ss_[i] * (1.f / 128.f) - mu * mu;
                mu_[i] = mu; rs_[i] = rsqrtf(var + 1e-5f);
            }
            float xs_[4] = {0.f, 0.f, 0.f, 0.f};
#pragma unroll
            for (int of = 0; of < 8; of++) {
                int j = of * 16 + lr;
                float lg = sScal[384 + j], lb2 = sScal[512 + j];
#pragma unroll
                for (int i = 0; i < 4; i++) {
                    float ov = (accs[of][i] - mu_[i]) * rs_[i] * lg + lb2;
                    accs[of][i] = ov;
                    xs_[i] += ov;
                }
            }
#pragma unroll
            for (int msk = 1; msk < 16; msk <<= 1)
#pragma unroll
                for (int i = 0; i < 4; i++) xs_[i] += __shfl_xor(xs_[i], msk);
            if (lr == 0) {
#pragma unroll
                for (int i = 0; i < 4; i++) {
                    int m = m0 + wm * 16 + lk * 4 + i;
                    if (m < 1000) {
                        float xv = xs_[i] * (1.f / 128.f);
                        x_out[(size_t)b * 1000 + m] = xv;
                        xb_out[(size_t)b * 1024 + m] = (__bf16)xv;
                    }
                }
            }
        }
        __syncthreads();
        if (wk == 0) {
#pragma unroll
            for (int of = 0; of < 8; of++)
#pragma unroll
                for (int i = 0; i < 4; i++)
                    sT[(of * 16 + lr) * SGS + wm * 16 + lk * 4 + i] = (__bf16)hnv[of][i];
        }
        __syncthreads();
        for (int q = tid; q < 128 * 8; q += 512) {
            int j = q >> 3, mc = (q & 7) * 8;
            if (m0 + mc < 1000)
                *(bf16x8*)&GhOut[((size_t)b * 128 + j) * KP + m0 + mc] = *(const bf16x8*)&sT[j * SGS + mc];
        }
        if (store_out) {
            __syncthreads();
            if (wk == 0) {
#pragma unroll
                for (int of = 0; of < 8; of++)
#pragma unroll
                    for (int i = 0; i < 4; i++)
                        sO[(wm * 16 + lk * 4 + i) * 136 + of * 16 + lr] = (__bf16)accs[of][i];
            }
            __syncthreads();
            for (int q = tid; q < 64 * 16; q += 512) {
                int ml = q >> 4, jc = (q & 15) * 8;
                int m = m0 + ml;
                if (m < 1000)
                    *(bf16x8*)&outT[((size_t)b * 1000 + m) * HH + jc] = *(const bf16x8*)&sO[ml * 136 + jc];
            }
        }
    }
#undef LOADG
}

// ---------------- GRU cell, MFMA, 32 rows/block, j split across wave-pairs ----------------
__global__ __launch_bounds__(256) void k_gru_mfma(const __bf16* __restrict__ Xb,
                                                  float* __restrict__ hg,
                                                  __bf16* __restrict__ Hb,
                                                  const __bf16* __restrict__ WihB,
                                                  const __bf16* __restrict__ WhhB,
                                                  const float* __restrict__ bih,
                                                  const float* __restrict__ bhh) {
    __shared__ float sB[512];
    int tid = threadIdx.x;
    int wave = tid >> 6, lane = tid & 63;
    int lr = lane & 15, lk = lane >> 4;
    int wm = wave & 1, wo = wave >> 1;
    int r0 = blockIdx.x * 32 + wm * 16;
    if (tid < 128) {
        sB[tid] = bih[tid] + bhh[tid];
        sB[128 + tid] = bih[128 + tid] + bhh[128 + tid];
        sB[256 + tid] = bih[256 + tid];
        sB[384 + tid] = bhh[256 + tid];
    }
    __syncthreads();

    f32x4 rz[8], ni[4], nh[4];
#pragma unroll
    for (int i = 0; i < 8; i++) rz[i] = (f32x4){0.f, 0.f, 0.f, 0.f};
#pragma unroll
    for (int i = 0; i < 4; i++) { ni[i] = (f32x4){0.f, 0.f, 0.f, 0.f}; nh[i] = (f32x4){0.f, 0.f, 0.f, 0.f}; }

    int arow = r0 + lr;
#pragma unroll
    for (int kk = 0; kk < 128; kk += 32) {
        bf16x8 xa = *(const bf16x8*)&Xb[(size_t)arow * HH + kk + lk * 8];
        bf16x8 ha = *(const bf16x8*)&Hb[(size_t)arow * HH + kk + lk * 8];
#pragma unroll
        for (int q = 0; q < 4; q++) {
            int orr = wo * 64 + q * 16 + lr;
            bf16x8 w0 = *(const bf16x8*)&WihB[(size_t)orr * HH + kk + lk * 8];
            rz[q] = __builtin_amdgcn_mfma_f32_16x16x32_bf16(xa, w0, rz[q], 0, 0, 0);
            bf16x8 w1 = *(const bf16x8*)&WhhB[(size_t)orr * HH + kk + lk * 8];
            rz[q] = __builtin_amdgcn_mfma_f32_16x16x32_bf16(ha, w1, rz[q], 0, 0, 0);
            bf16x8 w2 = *(const bf16x8*)&WihB[(size_t)(128 + orr) * HH + kk + lk * 8];
            rz[4 + q] = __builtin_amdgcn_mfma_f32_16x16x32_bf16(xa, w2, rz[4 + q], 0, 0, 0);
            bf16x8 w3 = *(const bf16x8*)&WhhB[(size_t)(128 + orr) * HH + kk + lk * 8];
            rz[4 + q] = __builtin_amdgcn_mfma_f32_16x16x32_bf16(ha, w3, rz[4 + q], 0, 0, 0);
            bf16x8 w4 = *(const bf16x8*)&WihB[(size_t)(256 + orr) * HH + kk + lk * 8];
            ni[q] = __builtin_amdgcn_mfma_f32_16x16x32_bf16(xa, w4, ni[q], 0, 0, 0);
            bf16x8 w5 = *(const bf16x8*)&WhhB[(size_t)(256 + orr) * HH + kk + lk * 8];
            nh[q] = __builtin_amdgcn_mfma_f32_16x16x32_bf16(ha, w5, nh[q], 0, 0, 0);
        }
    }
#pragma unroll
    for (int q = 0; q < 4; q++) {
        int j = wo * 64 + q * 16 + lr;
        float br = sB[j], bz = sB[128 + j], bni = sB[256 + j], bnh = sB[384 + j];
#pragma unroll
        for (int i = 0; i < 4; i++) {
            int row = r0 + lk * 4 + i;
            float rg = sigmoidf_(rz[q][i] + br);
            float zg = sigmoidf_(rz[4 + q][i] + bz);
            float hv = hg[(size_t)row * HH + j];
            float ng = tanhf(ni[q][i] + bni + rg * (nh[q][i] + bnh));
            float hp = (1.f - zg) * ng + zg * hv;
            hg[(size_t)row * HH + j] = hp;
            Hb[(size_t)row * HH + j] = (__bf16)hp;
        }
    }
}

// ---------------- head: proj -> relu MLP -> out, MFMA ----------------
__global__ __launch_bounds__(256) void k_head_mfma(const __bf16* __restrict__ Hb,
                                                   const __bf16* __restrict__ projB,
                                                   const float* __restrict__ pb,
                                                   const __bf16* __restrict__ w1B,
                                                   const float* __restrict__ b1,
                                                   const __bf16* __restrict__ w2B,
                                                   const float* __restrict__ b2,
                                                   float* __restrict__ out) {
    __shared__ __align__(16) __bf16 sH1[64 * 136];
    __shared__ __align__(16) __bf16 sH2[64 * 264];
    int tid = threadIdx.x;
    int r0 = blockIdx.x * 64;
    int wv = tid >> 6, lane = tid & 63;
    int lr = lane & 15, lk = lane >> 4;
    int arow = r0 + wv * 16 + lr;

    f32x4 a1[8];
#pragma unroll
    for (int i = 0; i < 8; i++) a1[i] = (f32x4){0.f, 0.f, 0.f, 0.f};
#pragma unroll
    for (int kk = 0; kk < 128; kk += 32) {
        bf16x8 xa = *(const bf16x8*)&Hb[(size_t)arow * HH + kk + lk * 8];
#pragma unroll
        for (int f = 0; f < 8; f++) {
            bf16x8 wb = *(const bf16x8*)&projB[(size_t)(f * 16 + lr) * HH + kk + lk * 8];
            a1[f] = __builtin_amdgcn_mfma_f32_16x16x32_bf16(xa, wb, a1[f], 0, 0, 0);
        }
    }
#pragma unroll
    for (int f = 0; f < 8; f++) {
        int j = f * 16 + lr;
        float bv = pb[j];
#pragma unroll
        for (int i = 0; i < 4; i++)
            sH1[(wv * 16 + lk * 4 + i) * 136 + j] = (__bf16)(a1[f][i] + bv);
    }
    __syncthreads();

    f32x4 a2[16];
#pragma unroll
    for (int i = 0; i < 16; i++) a2[i] = (f32x4){0.f, 0.f, 0.f, 0.f};
#pragma unroll
    for (int kk = 0; kk < 128; kk += 32) {
        bf16x8 pa = *(const bf16x8*)&sH1[(wv * 16 + lr) * 136 + kk + lk * 8];
#pragma unroll
        for (int f = 0; f < 16; f++) {
            bf16x8 wb = *(const bf16x8*)&w1B[(size_t)(f * 16 + lr) * HH + kk + lk * 8];
            a2[f] = __builtin_amdgcn_mfma_f32_16x16x32_bf16(pa, wb, a2[f], 0, 0, 0);
        }
    }
    __syncthreads();
#pragma unroll
    for (int f = 0; f < 16; f++) {
        int o = f * 16 + lr;
        float bv = b1[o];
#pragma unroll
        for (int i = 0; i < 4; i++)
            sH2[(wv * 16 + lk * 4 + i) * 264 + o] = (__bf16)fmaxf(a2[f][i] + bv, 0.f);
    }
    __syncthreads();

    f32x4 a3[8];
#pragma unroll
    for (int i = 0; i < 8; i++) a3[i] = (f32x4){0.f, 0.f, 0.f, 0.f};
#pragma unroll
    for (int kk = 0; kk < 256; kk += 32) {
        bf16x8 pa = *(const bf16x8*)&sH2[(wv * 16 + lr) * 264 + kk + lk * 8];
#pragma unroll
        for (int f = 0; f < 8; f++) {
            bf16x8 wb = *(const bf16x8*)&w2B[(size_t)(f * 16 + lr) * 256 + kk + lk * 8];
            a3[f] = __builtin_amdgcn_mfma_f32_16x16x32_bf16(pa, wb, a3[f], 0, 0, 0);
        }
    }
#pragma unroll
    for (int f = 0; f < 8; f++) {
        int j = f * 16 + lr;
        float bv = b2[j];
#pragma unroll
        for (int i = 0; i < 4; i++)
            out[(size_t)(r0 + wv * 16 + lk * 4 + i) * HH + j] = a3[f][i] + bv;
    }
}

extern "C" void kernel_launch(void* const* d_in, const int* in_sizes, int n_in,
                              void* d_out, int out_size, void* d_ws, size_t ws_size,
                              hipStream_t stream) {
    const float* inp    = (const float*)d_in[0];
    const float* adj    = (const float*)d_in[1];
    const float* gc1_w  = (const float*)d_in[2];
    const float* gc1_b  = (const float*)d_in[3];
    const float* gc2_w  = (const float*)d_in[4];
    const float* gc2_b  = (const float*)d_in[5];
    const float* ln_g   = (const float*)d_in[6];
    const float* ln_b   = (const float*)d_in[7];
    const float* res_w  = (const float*)d_in[8];
    const float* res_b  = (const float*)d_in[9];
    const float* wih    = (const float*)d_in[10];
    const float* whh    = (const float*)d_in[11];
    const float* bih    = (const float*)d_in[12];
    const float* bhh    = (const float*)d_in[13];
    const float* proj_w = (const float*)d_in[14];
    const float* proj_b = (const float*)d_in[15];
    const float* ow1    = (const float*)d_in[16];
    const float* ob1    = (const float*)d_in[17];
    const float* ow2    = (const float*)d_in[18];
    const float* ob2    = (const float*)d_in[19];
    float* out = (float*)d_out;

    char* ws = (char*)d_ws;
    size_t off = 0;
    __bf16* Lb  = (__bf16*)(ws + off); off += (size_t)KP * KP * 2;        // 2 MB
    __bf16* Gh0 = (__bf16*)(ws + off); off += (size_t)BB * 128 * KP * 2;  // 4 MB
    __bf16* Gh1 = (__bf16*)(ws + off); off += (size_t)BB * 128 * KP * 2;
    __bf16* Grh = (__bf16*)(ws + off); off += (size_t)BB * 128 * KP * 2;
    __bf16* Xall= (__bf16*)(ws + off); off += (size_t)TT * BB * 1024 * 2; // 393 KB
    __bf16* xbB = (__bf16*)(ws + off); off += (size_t)BB * 1024 * 2;
    __bf16* xbA = (__bf16*)(ws + off); off += (size_t)BB * 1024 * 2;
    size_t zgrp1 = off;                                                    // memset group 1 end
    float* h0   = (float*)(ws + off);  off += (size_t)NROW * HH * 4;
    float* h1   = (float*)(ws + off);  off += (size_t)NROW * HH * 4;
    float* hg   = (float*)(ws + off);  off += (size_t)NROW * HH * 4;
    __bf16* Hb  = (__bf16*)(ws + off); off += (size_t)NROW * HH * 2;
    float* u    = (float*)(ws + off);  off += (size_t)NROW * HH * 4;
    __bf16* outT= (__bf16*)(ws + off); off += (size_t)NROW * HH * 2;
    float* xA   = (float*)(ws + off);  off += NROW * 4;
    float* xB   = (float*)(ws + off);  off += NROW * 4;
    __bf16* W1t = (__bf16*)(ws + off); off += (size_t)2 * 256 * CP2 * 2;
    __bf16* W2t = (__bf16*)(ws + off); off += (size_t)2 * 128 * CP2 * 2;
    __bf16* WihB= (__bf16*)(ws + off); off += 49152 * 2;
    __bf16* WhhB= (__bf16*)(ws + off); off += 49152 * 2;
    __bf16* projB=(__bf16*)(ws + off); off += 16384 * 2;
    __bf16* w1B = (__bf16*)(ws + off); off += 32768 * 2;
    __bf16* w2B = (__bf16*)(ws + off); off += 32768 * 2;
    float* a_sm = u;   // overlay: softmax scratch used before u's first write

    hipMemsetAsync(Lb, 0, zgrp1, stream);                               // Lb..xbA
    hipMemsetAsync(h0, 0, (size_t)NROW * HH * 8, stream);               // h0,h1
    hipMemsetAsync(hg, 0, (size_t)NROW * HH * 6, stream);               // hg,Hb

    k_softmax<<<NN, 256, 0, stream>>>(adj, a_sm);
    k_build_Lt<<<dim3(16, 16), 256, 0, stream>>>(a_sm, Lb);
    k_prep<<<1184, 256, 0, stream>>>(wih, whh, proj_w, ow1, ow2, gc1_w, gc2_w,
                                     WihB, WhhB, projB, w1B, w2B, W1t, W2t);
    k_prep_x<<<768, 256, 0, stream>>>(inp, Xall);

    dim3 fgrid(16, 16);
    for (int t = 0; t < TT; t++) {
        const __bf16* xt = Xall + (size_t)t * BB * 1024;
        const float* xs0 = inp + (size_t)t * NN;
        // layer 0
        k_fused<0><<<fgrid, 512, 0, stream>>>(Lb, Gh0, xt, nullptr, 0, W1t, gc1_b,
                                              Grh, u, nullptr, nullptr, nullptr, nullptr,
                                              nullptr, nullptr, nullptr, nullptr, nullptr, 0);
        k_fused<1><<<fgrid, 512, 0, stream>>>(Lb, Grh, xt, xs0, TT * NN, W2t, gc2_b,
                                              nullptr, u, h0, res_w, res_b, ln_g, ln_b,
                                              xB, xbB, Gh0, nullptr, 0);
        // layer 1
        k_fused<0><<<fgrid, 512, 0, stream>>>(Lb, Gh1, xbB, nullptr, 0, W1t + 256 * CP2, gc1_b + 256,
                                              Grh, u, nullptr, nullptr, nullptr, nullptr,
                                              nullptr, nullptr, nullptr, nullptr, nullptr, 0);
        k_fused<1><<<fgrid, 512, 0, stream>>>(Lb, Grh, xbB, xB, NN, W2t + 128 * CP2, gc2_b + 128,
                                              nullptr, u, h1, res_w, res_b, ln_g + 128, ln_b + 128,
                                              xA, xbA, Gh1, outT, 1);
        k_gru_mfma<<<500, 256, 0, stream>>>(outT, hg, Hb, WihB, WhhB, bih, bhh);
    }
    k_head_mfma<<<250, 256, 0, stream>>>(Hb, projB, proj_b, w1B, ob1, w2B, ob2, out);
}